// Round 7
// baseline (330.581 us; speedup 1.0000x reference)
//
#include <hip/hip_runtime.h>

// FFT-conv: y = real(ifft2( sum_i K[o,i] * fft2(x[b,i]) )) + bias
// B=32, CIN=64, COUT=128, H=W=56.
// Hermitian symmetry: only spectral rows kh=0..28 stored (NFH=1624 bins).
// Pipeline (3 worker dispatches after ksetup):
//   kfwd : forward FFT2, 2 images / 512-thr block, bf16 MFMA
//   kmix : per-bin complex channel mix, bf16 MFMA GEMM, WITH FUSED K
//          transpose: each block reads its K tile [32o][64i][8f] straight
//          from the fp32 [o][i][f] layout (8 bins = full 32B sector, K
//          fetched exactly once), converts to bf16, scatters into a
//          XOR-swizzled 128KB LDS. No kprep kernel, no Kb intermediate.
//   kinv : inverse FFT2, 2 images/block; ZT aliases dead Y region (48 KB)

#define HH 56
#define NF 3136      // 56*56
#define KH 29        // stored spectral rows
#define NFH 1624     // 29*56
constexpr int B = 32, CIN = 64, COUT = 128;
constexpr float PI2 = 6.283185307179586f;

typedef unsigned short u16;
typedef __attribute__((ext_vector_type(8))) short s8v;   // 8 x bf16 (A/B frag)
typedef __attribute__((ext_vector_type(4))) float f4v;   // C/D frag
typedef __attribute__((ext_vector_type(4))) int i4v;

#define MFMA(a, b, c) __builtin_amdgcn_mfma_f32_16x16x32_bf16(a, b, c, 0, 0, 0)

__device__ __host__ inline short f2bf(float f) {
    unsigned u = __builtin_bit_cast(unsigned, f);
    u += 0x7fffu + ((u >> 16) & 1u);      // round-to-nearest-even
    return (short)(u >> 16);
}

__device__ inline unsigned pk2(float a, float b) {   // pack 2 floats -> 2 bf16
    return (unsigned)(u16)f2bf(a) | ((unsigned)(u16)f2bf(b) << 16);
}

__device__ inline s8v negbf(s8v a) {       // flip bf16 sign bits
    i4v t = __builtin_bit_cast(i4v, a);
    t ^= (int)0x80008000u;
    return __builtin_bit_cast(s8v, t);
}

// ---------------------------------------------------------------------------
// Constant pool in d_ws (shorts):
//   Cw  [64][72] @0     : cos(2*pi*m*n/56), m<56&&n<56 else 0   (symmetric)
//   Sw  [64][72] @4608  : +sin(...)                             (symmetric)
//   A2C [64][40] @13824 : wgt(kh)*cos(2*pi*h*kh/56)/3136  (h<56,kh<29 else 0)
//   A2S [64][40] @16384 : -wgt(kh)*sin(...)/3136
__global__ __launch_bounds__(256) void ksetup(short* __restrict__ cpool) {
    int i = blockIdx.x * 256 + threadIdx.x;
    if (i < 4608) {
        int m = i / 72, n = i % 72;
        float c = 0.f, s = 0.f;
        if (m < 56 && n < 56) {
            float ang = PI2 * (float)((m * n) % 56) / 56.f;
            c = cosf(ang); s = sinf(ang);
        }
        cpool[i]        = f2bf(c);
        cpool[4608 + i] = f2bf(s);
    } else if (i < 7168) {
        int j = i - 4608;
        int h = j / 40, kh = j % 40;
        float c = 0.f, s = 0.f;
        if (h < 56 && kh < 29) {
            float w = (kh == 0 || kh == 28) ? 1.f : 2.f;
            float ang = PI2 * (float)((h * kh) % 56) / 56.f;
            float sc = w * (1.f / 3136.f);
            c = sc * cosf(ang);
            s = -sc * sinf(ang);
        }
        cpool[13824 + j] = f2bf(c);
        cpool[16384 + j] = f2bf(s);
    }
}

// ---------------------------------------------------------------------------
// kfwd: forward FFT2, 2 images per 512-thread block (waves 0-3 img0, 4-7 img1).
//   stage1: S1[h][kw]  = sum_w  x[h][w] * e^{-2pi i w kw/56}
//   stage2: X[kh][kw]  = sum_h  e^{-2pi i h kh/56} * S1[h][kw]   (kh<29 stored)
// Output: bf16 ushort2 (r,i) at [b*CIN+i][kh*56+kw].
__global__ __launch_bounds__(512) void kfwd(const float* __restrict__ x,
                                            const short* __restrict__ cpool,
                                            ushort2* __restrict__ Xb) {
    __shared__ __align__(16) short Cw[4608], Sw[4608];
    __shared__ __align__(16) short xs[2][4608];            // [h][72] bf16
    __shared__ __align__(16) short T1r[2][4608], T1i[2][4608]; // [kw][72]
    const int tid = threadIdx.x;
    {
        const int4* src = (const int4*)cpool;
        for (int i = tid; i < 576; i += 512) {
            ((int4*)Cw)[i] = src[i];
            ((int4*)Sw)[i] = src[576 + i];
        }
    }
    for (int i = tid; i < 4608; i += 512) ((int*)xs)[i] = 0;   // both images
    __syncthreads();
    const int half = tid >> 8, tid2 = tid & 255;
    const float* xp = x + (size_t)(blockIdx.x * 2 + half) * NF;
    short* xsh = xs[half];
    for (int c = tid2; c < 784; c += 256) {        // 56 rows x 14 float4
        int r = c / 14, c4 = (c % 14) * 4;
        float4 v = *(const float4*)&xp[r * 56 + c4];
        *(uint2*)&xsh[r * 72 + c4] = make_uint2(pk2(v.x, v.y), pk2(v.z, v.w));
    }
    __syncthreads();

    const int lane = tid & 63;
    const int wv = tid >> 6;
    const int hw = wv >> 2;            // image half (== tid>>8)
    const int nt = wv & 3;             // N-tile strip within image
    const int q = lane >> 4, l15 = lane & 15;

    // ---- stage 1: A = xs[h][w], B = (C - iS)[w][kw]  (B read via symmetry)
    f4v aR[4] = {}, aI[4] = {};
    for (int ks = 0; ks < 2; ++ks) {
        const int bo = (nt * 16 + l15) * 72 + ks * 32 + q * 8;
        s8v bC  = *(const s8v*)&Cw[bo];
        s8v bSN = negbf(*(const s8v*)&Sw[bo]);
        for (int mt = 0; mt < 4; ++mt) {
            s8v a = *(const s8v*)&xs[hw][(mt * 16 + l15) * 72 + ks * 32 + q * 8];
            aR[mt] = MFMA(a, bC, aR[mt]);
            aI[mt] = MFMA(a, bSN, aI[mt]);
        }
    }
    for (int mt = 0; mt < 4; ++mt) {
        int o = (nt * 16 + l15) * 72 + mt * 16 + q * 4;     // [kw][h]
        *(uint2*)&T1r[hw][o] = make_uint2(pk2(aR[mt][0], aR[mt][1]),
                                          pk2(aR[mt][2], aR[mt][3]));
        *(uint2*)&T1i[hw][o] = make_uint2(pk2(aI[mt][0], aI[mt][1]),
                                          pk2(aI[mt][2], aI[mt][3]));
    }
    __syncthreads();

    // ---- stage 2: A = (C2|S2)[kh][h] (top 32 rows of Cw/Sw), B = S1[h][kw]
    //      Xr = C2*S1r + S2*S1i ;  Xi = C2*S1i - S2*S1r
    f4v xr[2] = {}, xi2[2] = {};
    for (int ks = 0; ks < 2; ++ks) {
        const int bo = (nt * 16 + l15) * 72 + ks * 32 + q * 8;
        s8v br = *(const s8v*)&T1r[hw][bo];
        s8v bi = *(const s8v*)&T1i[hw][bo];
        for (int mt = 0; mt < 2; ++mt) {
            const int ao = (mt * 16 + l15) * 72 + ks * 32 + q * 8;
            s8v aC  = *(const s8v*)&Cw[ao];
            s8v aS  = *(const s8v*)&Sw[ao];
            s8v aSN = negbf(aS);
            xr[mt]  = MFMA(aC, br, xr[mt]);
            xr[mt]  = MFMA(aS, bi, xr[mt]);
            xi2[mt] = MFMA(aC, bi, xi2[mt]);
            xi2[mt] = MFMA(aSN, br, xi2[mt]);
        }
    }
    ushort2* op = Xb + (size_t)(blockIdx.x * 2 + hw) * NFH;
    const int kw = nt * 16 + l15;
    if (kw < 56) {
        for (int mt = 0; mt < 2; ++mt)
            for (int r = 0; r < 4; ++r) {
                int kh = mt * 16 + q * 4 + r;
                if (kh < 29)
                    op[kh * 56 + kw] = make_ushort2((u16)f2bf(xr[mt][r]),
                                                    (u16)f2bf(xi2[mt][r]));
            }
    }
}

// ---------------------------------------------------------------------------
// kmix: per-bin complex channel mix as bf16 MFMA GEMM, fused K transpose.
//   Y[b][o](f) = sum_i X[b][i](f) * K[o][i](f)
// Grid (203, 4): block = 8 bins x 32 outs, 512 threads = 8 waves.
// LDS 128 KB, 4 swizzled plane sets of [8 f][32 rows][64 elem] bf16:
//   Xr @0, Xi @32768, Kr @65536, Ki @98304; within a plane (4096 B) the
//   element (row,e) lives at byte (row*128 + e*2) ^ ((row&7)<<4)  [T2].
// K read DIRECTLY from fp32 [o][i][3136]: 8 consecutive bins per (o,i) row
// = one full 32B sector; K fetched exactly once across the grid.
// Wave wv: ffh=wv>>2 (4-bin half), bh=(wv>>1)&1 (b half), ot=wv&1 (o half).
__global__ __launch_bounds__(512) void kmix(const ushort2* __restrict__ Xb,
                                            const float* __restrict__ Kr,
                                            const float* __restrict__ Ki,
                                            ushort2* __restrict__ Yb) {
    __shared__ __align__(16) char pool[131072];
    const int tid = threadIdx.x;
    const int f0 = blockIdx.x * 8;
    const int o0 = blockIdx.y * 32;

    // ---- stage X: 2048 rows (b*64+i) x 8 bins (32B each, bf16 ushort2)
    for (int it = 0; it < 4; ++it) {
        int row = it * 512 + tid;
        const uint4* src = (const uint4*)(Xb + (size_t)row * NFH + f0);
        uint4 v0 = src[0], v1 = src[1];
        int b = row >> 6, i = row & 63;
        int sw = (b * 128 + i * 2) ^ ((b & 7) << 4);
        unsigned uu[8] = {v0.x, v0.y, v0.z, v0.w, v1.x, v1.y, v1.z, v1.w};
        #pragma unroll
        for (int ff = 0; ff < 8; ++ff) {
            *(u16*)(pool + ff * 4096 + sw)         = (u16)uu[ff];
            *(u16*)(pool + 32768 + ff * 4096 + sw) = (u16)(uu[ff] >> 16);
        }
    }
    // ---- stage K: 2048 rows (o_l*64+i), fp32 -> bf16, 8 bins (2x16B sector)
    for (int it = 0; it < 4; ++it) {
        int r = it * 512 + tid;
        int ol = r >> 6, i = r & 63;
        size_t g = ((size_t)((o0 + ol) * CIN + i)) * NF + f0;
        int sw = (ol * 128 + i * 2) ^ ((ol & 7) << 4);
        {
            float4 a = *(const float4*)&Kr[g];
            float4 c = *(const float4*)&Kr[g + 4];
            float vv[8] = {a.x, a.y, a.z, a.w, c.x, c.y, c.z, c.w};
            #pragma unroll
            for (int ff = 0; ff < 8; ++ff)
                *(u16*)(pool + 65536 + ff * 4096 + sw) = (u16)f2bf(vv[ff]);
        }
        {
            float4 a = *(const float4*)&Ki[g];
            float4 c = *(const float4*)&Ki[g + 4];
            float vv[8] = {a.x, a.y, a.z, a.w, c.x, c.y, c.z, c.w};
            #pragma unroll
            for (int ff = 0; ff < 8; ++ff)
                *(u16*)(pool + 98304 + ff * 4096 + sw) = (u16)f2bf(vv[ff]);
        }
    }
    __syncthreads();

    const int lane = tid & 63;
    const int wv = tid >> 6;
    const int ffh = wv >> 2, bh = (wv >> 1) & 1, ot = wv & 1;
    const int q = lane >> 4, l15 = lane & 15;

    const int bb = bh * 16 + l15;                 // A row (b)
    const int oo = ot * 16 + l15;                 // B col (o_local)
    const int xa0 = (bb * 128 + q * 16)      ^ ((bb & 7) << 4);
    const int xa1 = (bb * 128 + q * 16 + 64) ^ ((bb & 7) << 4);
    const int ka0 = (oo * 128 + q * 16)      ^ ((oo & 7) << 4);
    const int ka1 = (oo * 128 + q * 16 + 64) ^ ((oo & 7) << 4);

    unsigned pk[4][4];                            // [r][ffc] packed (yr|yi<<16)

    #pragma unroll
    for (int ffc = 0; ffc < 4; ++ffc) {
        const int fb = (ffh * 4 + ffc) * 4096;
        s8v axr0 = *(const s8v*)(pool + fb + xa0);
        s8v axr1 = *(const s8v*)(pool + fb + xa1);
        s8v axi0 = *(const s8v*)(pool + 32768 + fb + xa0);
        s8v axi1 = *(const s8v*)(pool + 32768 + fb + xa1);
        s8v bkr0 = *(const s8v*)(pool + 65536 + fb + ka0);
        s8v bkr1 = *(const s8v*)(pool + 65536 + fb + ka1);
        s8v bki0 = *(const s8v*)(pool + 98304 + fb + ka0);
        s8v bki1 = *(const s8v*)(pool + 98304 + fb + ka1);
        s8v axn0 = negbf(axi0), axn1 = negbf(axi1);
        f4v yr = {}, yi = {};
        yr = MFMA(axr0, bkr0, yr);   // Yr = Xr*Kr - Xi*Ki
        yr = MFMA(axn0, bki0, yr);
        yr = MFMA(axr1, bkr1, yr);
        yr = MFMA(axn1, bki1, yr);
        yi = MFMA(axr0, bki0, yi);   // Yi = Xr*Ki + Xi*Kr
        yi = MFMA(axi0, bkr0, yi);
        yi = MFMA(axr1, bki1, yi);
        yi = MFMA(axi1, bkr1, yi);
        #pragma unroll
        for (int r = 0; r < 4; ++r)
            pk[r][ffc] = (unsigned)(u16)f2bf(yr[r]) |
                         ((unsigned)(u16)f2bf(yi[r]) << 16);
    }

    // ---- burst write: one 16B-aligned 16B run (4 bins) per (b,o) row
    const int o_out = o0 + oo;
    #pragma unroll
    for (int r = 0; r < 4; ++r) {
        const int b_out = bh * 16 + q * 4 + r;
        uint4* dst = (uint4*)(Yb + (size_t)(b_out * COUT + o_out) * NFH
                              + f0 + ffh * 4);
        *dst = make_uint4(pk[r][0], pk[r][1], pk[r][2], pk[r][3]);
    }
}

// ---------------------------------------------------------------------------
// kinv: inverse FFT2, 2 images per 512-thread block (waves 0-3 / 4-7).
//   inv1: Z[kh][w] = sum_kw Y[kh][kw] * e^{+2pi i kw w/56}
//   inv2: y[h][w]  = sum_kh wgt(kh)*(Zr*cos - Zi*sin)/3136 + bias
// LDS: ZT aliases the (dead after inv1) Y region -> 48 KB -> 3 blocks/CU.
__global__ __launch_bounds__(512) void kinv(const ushort2* __restrict__ Yf,
                                            const short* __restrict__ cpool,
                                            const float* __restrict__ bias,
                                            float* __restrict__ out) {
    __shared__ __align__(16) char pool[49152];
    short* Cw    = (short*)pool;        // [4608]
    short* Sw    = Cw + 4608;           // [4608]
    short* A2C   = Sw + 4608;           // [2560]
    short* A2S   = A2C + 2560;          // [2560]
    short* Ybase = A2S + 2560;          // 20480 B shared region
    short* Yr    = Ybase;               // [2][2304]  [kh][72]
    short* Yi    = Yr + 4608;
    short* ZTr   = Ybase;               // [2][2560]  [w][40]  (aliases Y)
    short* ZTi   = ZTr + 5120;
    const int tid = threadIdx.x;
    {
        const int4* src = (const int4*)cpool;
        for (int i = tid; i < 576; i += 512) {
            ((int4*)Cw)[i] = src[i];
            ((int4*)Sw)[i] = src[576 + i];
        }
        for (int i = tid; i < 320; i += 512) {
            ((int4*)A2C)[i] = src[1728 + i];
            ((int4*)A2S)[i] = src[2048 + i];
        }
    }
    for (int i = tid; i < 4608; i += 512) ((int*)Ybase)[i] = 0;  // Yr+Yi full
    __syncthreads();
    const int half = tid >> 8, tid2 = tid & 255;
    const ushort2* yp = Yf + (size_t)(blockIdx.x * 2 + half) * NFH;
    short* Yrh = Yr + half * 2304;
    short* Yih = Yi + half * 2304;
    for (int c = tid2; c < 406; c += 256) {        // 1624/4 uint4 chunks
        uint4 v = *(const uint4*)&yp[c * 4];
        int f = c * 4, kh = f / 56, kwb = f % 56;  // 56%4==0: no row crossing
        int o = kh * 72 + kwb;
        *(uint2*)&Yrh[o] = make_uint2((v.x & 0xffffu) | (v.y << 16),
                                      (v.z & 0xffffu) | (v.w << 16));
        *(uint2*)&Yih[o] = make_uint2((v.x >> 16) | (v.y & 0xffff0000u),
                                      (v.z >> 16) | (v.w & 0xffff0000u));
    }
    __syncthreads();

    const int lane = tid & 63;
    const int wv = tid >> 6;
    const int hw = wv >> 2, nt = wv & 3;
    const int q = lane >> 4, l15 = lane & 15;

    // ---- inv1: A = Y[kh][kw], B = (C + iS)[kw][w] via symmetry
    //      Zr = Yr*C - Yi*S ;  Zi = Yr*S + Yi*C
    f4v zr[2] = {}, zi[2] = {};
    for (int ks = 0; ks < 2; ++ks) {
        const int bo = (nt * 16 + l15) * 72 + ks * 32 + q * 8;
        s8v bC = *(const s8v*)&Cw[bo];
        s8v bS = *(const s8v*)&Sw[bo];
        for (int mt = 0; mt < 2; ++mt) {
            const int ao = hw * 2304 + (mt * 16 + l15) * 72 + ks * 32 + q * 8;
            s8v ar  = *(const s8v*)&Yr[ao];
            s8v ai  = *(const s8v*)&Yi[ao];
            s8v ain = negbf(ai);
            zr[mt] = MFMA(ar, bC, zr[mt]);
            zr[mt] = MFMA(ain, bS, zr[mt]);
            zi[mt] = MFMA(ar, bS, zi[mt]);
            zi[mt] = MFMA(ai, bC, zi[mt]);
        }
    }
    __syncthreads();   // Y region dead; ZT aliases it
    for (int mt = 0; mt < 2; ++mt) {
        int o = hw * 2560 + (nt * 16 + l15) * 40 + mt * 16 + q * 4;  // [w][kh]
        *(uint2*)&ZTr[o] = make_uint2(pk2(zr[mt][0], zr[mt][1]),
                                      pk2(zr[mt][2], zr[mt][3]));
        *(uint2*)&ZTi[o] = make_uint2(pk2(zi[mt][0], zi[mt][1]),
                                      pk2(zi[mt][2], zi[mt][3]));
    }
    __syncthreads();

    // ---- inv2: A = A2C/A2S [h][kh] (K=32, one k-step), B = Z[kh][w]
    f4v yv[4] = {};
    {
        const int bo = hw * 2560 + (nt * 16 + l15) * 40 + q * 8;
        s8v br = *(const s8v*)&ZTr[bo];
        s8v bi = *(const s8v*)&ZTi[bo];
        for (int mt = 0; mt < 4; ++mt) {
            const int ao = (mt * 16 + l15) * 40 + q * 8;
            s8v ac  = *(const s8v*)&A2C[ao];
            s8v as_ = *(const s8v*)&A2S[ao];
            yv[mt] = MFMA(ac, br, yv[mt]);
            yv[mt] = MFMA(as_, bi, yv[mt]);
        }
    }
    const int img = blockIdx.x * 2 + hw;
    const float bv = bias[img & (COUT - 1)];
    float* opx = out + (size_t)img * NF;
    const int w = nt * 16 + l15;
    if (w < 56) {
        for (int mt = 0; mt < 4; ++mt)
            for (int r = 0; r < 4; ++r) {
                int h = mt * 16 + q * 4 + r;
                if (h < 56) opx[h * 56 + w] = yv[mt][r] + bv;
            }
    }
}

// ---------------------------------------------------------------------------
extern "C" void kernel_launch(void* const* d_in, const int* in_sizes, int n_in,
                              void* d_out, int out_size, void* d_ws, size_t ws_size,
                              hipStream_t stream) {
    const float* x    = (const float*)d_in[0];
    const float* Kr   = (const float*)d_in[1];
    const float* Ki   = (const float*)d_in[2];
    const float* bias = (const float*)d_in[3];

    // Workspace layout (~40 MB total; Kb intermediate eliminated):
    //   cpool  @0          : 40960 B constants
    //   Xb     @40960      : bf16 [B][CIN][1624]  ushort2   13,307,904 B
    //   Yb     @+13307904  : bf16 [B][COUT][1624] ushort2   26,615,808 B
    short*   cpool = (short*)d_ws;
    ushort2* Xb = (ushort2*)((char*)d_ws + 40960);
    ushort2* Yb = (ushort2*)((char*)d_ws + 40960 + 13307904);

    hipLaunchKernelGGL(ksetup, dim3(28), dim3(256), 0, stream, cpool);
    hipLaunchKernelGGL(kfwd, dim3(B * CIN / 2), dim3(512), 0, stream,
                       x, cpool, Xb);
    hipLaunchKernelGGL(kmix, dim3(NFH / 8, 4), dim3(512), 0, stream,
                       Xb, Kr, Ki, Yb);
    hipLaunchKernelGGL(kinv, dim3(B * COUT / 2), dim3(512), 0, stream,
                       Yb, cpool, bias, (float*)d_out);
}